// Round 13
// baseline (594.945 us; speedup 1.0000x reference)
//
#include <hip/hip_runtime.h>
#include <cstdint>
#include <cstddef>

#define NN 50000
#define EE 800000
#define ET 850000   // EE + NN self loops

typedef unsigned short ushort_t;
typedef unsigned int uint_t;
using frag_ab = __attribute__((ext_vector_type(8))) short;   // 8 bf16
using f32x4   = __attribute__((ext_vector_type(4))) float;
using f32x2   = __attribute__((ext_vector_type(2))) float;

__device__ inline ushort_t f2b(float x) {
  union { float f; unsigned int u; } c; c.f = x;
  unsigned int u = c.u;
  u += 0x7fffu + ((u >> 16) & 1u);   // round-to-nearest-even
  return (ushort_t)(u >> 16);
}
__device__ inline float b2f(uint_t u) {
  union { unsigned int u; float f; } c; c.u = u << 16;
  return c.f;
}
// unpack uint (2 bf16) -> f32x2 {lo, hi}
__device__ inline f32x2 unp2(uint_t u) {
  union { uint_t u; float f; } lo, hi;
  lo.u = u << 16; hi.u = u & 0xffff0000u;
  f32x2 r; r.x = lo.f; r.y = hi.f; return r;
}

// async global->LDS, 16B per lane; LDS dest = wave-uniform base + lane*16
__device__ inline void gload16(const ushort_t* g, ushort_t* l) {
  __builtin_amdgcn_global_load_lds(
      (const __attribute__((address_space(1))) unsigned int*)g,
      (__attribute__((address_space(3))) unsigned int*)l, 16, 0, 0);
}

// ---------------------------------------------------------------- CSR build
__global__ __launch_bounds__(256) void k_count(const int* __restrict__ edge,
                                               int* __restrict__ counts) {
  int e = blockIdx.x * 256 + threadIdx.x;
  if (e >= ET) return;
  int dd = (e < EE) ? edge[EE + e] : (e - EE);
  atomicAdd(&counts[dd], 1);
}

__global__ __launch_bounds__(1024) void k_scan1(const int* __restrict__ counts,
                                                int* __restrict__ scn,
                                                int* __restrict__ bsum) {
  __shared__ int tmp[1024];
  int tid = threadIdx.x;
  int idx = blockIdx.x * 1024 + tid;
  int v = (idx < NN) ? counts[idx] : 0;
  tmp[tid] = v;
  __syncthreads();
  for (int o = 1; o < 1024; o <<= 1) {
    int u = (tid >= o) ? tmp[tid - o] : 0;
    __syncthreads();
    tmp[tid] += u;
    __syncthreads();
  }
  if (idx < NN) scn[idx] = tmp[tid] - v;
  if (tid == 1023) bsum[blockIdx.x] = tmp[1023];
}

__global__ __launch_bounds__(64) void k_scan2(const int* __restrict__ bsum,
                                              int* __restrict__ boff) {
  int l = threadIdx.x;
  const int NB = (NN + 1023) / 1024;           // 49
  int v = (l < NB) ? bsum[l] : 0;
  int own = v;
  for (int o = 1; o < 64; o <<= 1) {
    int u = __shfl_up(v, o);
    if (l >= o) v += u;
  }
  if (l < NB) boff[l] = v - own;
}

__global__ __launch_bounds__(1024) void k_scan3(const int* __restrict__ scn,
                                                const int* __restrict__ boff,
                                                int* __restrict__ row_ptr,
                                                int* __restrict__ cursor) {
  int idx = blockIdx.x * 1024 + threadIdx.x;
  if (idx < NN) {
    int v = scn[idx] + boff[blockIdx.x];
    row_ptr[idx] = v;
    cursor[idx] = v;
  }
  if (idx == 0) row_ptr[NN] = ET;
}

__global__ __launch_bounds__(256) void k_fill(const int* __restrict__ edge,
                                              int* __restrict__ cursor,
                                              int* __restrict__ col_src) {
  int e = blockIdx.x * 256 + threadIdx.x;
  if (e >= ET) return;
  int ss, dd;
  if (e < EE) { ss = edge[e]; dd = edge[EE + e]; }
  else        { ss = dd = e - EE; }
  int pos = atomicAdd(&cursor[dd], 1);
  col_src[pos] = ss;
}

// ---------------------------------------------------- weight prep (bf16, [n][k])
__global__ __launch_bounds__(256) void k_prep_w(const float* __restrict__ fc_w,
                                                const float* __restrict__ W1,
                                                const float* __restrict__ Wm,
                                                const float* __restrict__ W6,
                                                ushort_t* __restrict__ fcWt,
                                                ushort_t* __restrict__ W1t,
                                                ushort_t* __restrict__ Wmt,
                                                ushort_t* __restrict__ W6t) {
  int i = blockIdx.x * 256 + threadIdx.x;
  if (i < 128 * 64) { int n = i >> 6, k = i & 63; fcWt[i] = f2b(fc_w[k * 128 + n]); return; }
  i -= 128 * 64;
  if (i < 256 * 128) { int n = i >> 7, k = i & 127; W1t[i] = f2b(W1[k * 256 + n]); return; }
  i -= 256 * 128;
  if (i < 4 * 256 * 256) {
    int l = i >> 16, r2 = i & 65535, n = r2 >> 8, k = r2 & 255;
    Wmt[i] = f2b(Wm[(size_t)l * 65536 + k * 256 + n]); return;
  }
  i -= 4 * 256 * 256;
  if (i < 128 * 256) { int n = i >> 8, k = i & 255; W6t[i] = f2b(W6[k * 128 + n]); return; }
}

// ---------------------------------------------- fc GEMM (f32 input)
__global__ __launch_bounds__(256) void k_gemm_f32(const float* __restrict__ A,
                                                  const ushort_t* __restrict__ Bt,
                                                  ushort_t* __restrict__ C,
                                                  int M, int K, int Nc,
                                                  const float* __restrict__ bias) {
  __shared__ ushort_t As[128 * 40];
  __shared__ ushort_t Bs[128 * 40];
  int row0 = blockIdx.x * 128;
  int col0 = blockIdx.y * 128;
  int t = threadIdx.x;
  int lane = t & 63, w = t >> 6;
  int wr = w >> 1, wc = w & 1;
  int r = lane & 15, kg = lane >> 4;

  f32x4 acc[4][4];
#pragma unroll
  for (int m = 0; m < 4; ++m)
#pragma unroll
    for (int n = 0; n < 4; ++n) acc[m][n] = (f32x4){0.f, 0.f, 0.f, 0.f};

  for (int k0 = 0; k0 < K; k0 += 32) {
    __syncthreads();
#pragma unroll
    for (int rep = 0; rep < 4; ++rep) {
      int c = t + rep * 256;
      int row = c >> 3, kc = c & 7;
      int grow = row0 + row;
      if (grow < M) {
        float4 v = *(const float4*)&A[(size_t)grow * K + k0 + kc * 4];
        ushort4 u;
        u.x = f2b(v.x); u.y = f2b(v.y); u.z = f2b(v.z); u.w = f2b(v.w);
        *(ushort4*)&As[row * 40 + kc * 4] = u;
      }
    }
#pragma unroll
    for (int rep = 0; rep < 2; ++rep) {
      int c = t + rep * 256;
      int row = c >> 2, kc = c & 3;
      uint4 v = *(const uint4*)&Bt[(size_t)(col0 + row) * K + k0 + kc * 8];
      *(uint4*)&Bs[row * 40 + kc * 8] = v;
    }
    __syncthreads();

    frag_ab a[4], b[4];
#pragma unroll
    for (int m = 0; m < 4; ++m)
      a[m] = *(const frag_ab*)&As[(wr * 64 + m * 16 + r) * 40 + kg * 8];
#pragma unroll
    for (int n = 0; n < 4; ++n)
      b[n] = *(const frag_ab*)&Bs[(wc * 64 + n * 16 + r) * 40 + kg * 8];
#pragma unroll
    for (int m = 0; m < 4; ++m)
#pragma unroll
      for (int n = 0; n < 4; ++n)
        acc[m][n] = __builtin_amdgcn_mfma_f32_16x16x32_bf16(a[m], b[n], acc[m][n], 0, 0, 0);
  }

#pragma unroll
  for (int m = 0; m < 4; ++m) {
    int gr0 = row0 + wr * 64 + m * 16 + kg * 4;
#pragma unroll
    for (int q = 0; q < 4; ++q) {
      int grow = gr0 + q;
      if (grow >= M) continue;
#pragma unroll
      for (int n = 0; n < 4; ++n) {
        int gcol = col0 + wc * 64 + n * 16 + r;
        float val = acc[m][n][q] + bias[gcol];
        val = fmaxf(val, 0.f);
        C[(size_t)grow * Nc + gcol] = f2b(val);
      }
    }
  }
}

// ------------------------------- GAT GEMM: bf16, BK=64, global_load_lds + swizzle
__global__ __launch_bounds__(256) void k_gemm64(const ushort_t* __restrict__ A,
                                                const ushort_t* __restrict__ Bt,
                                                ushort_t* __restrict__ C,
                                                int M, int K, int Nc,
                                                const float* __restrict__ a_src,
                                                const float* __restrict__ a_dst,
                                                float* __restrict__ sbuf,
                                                float* __restrict__ dbuf,
                                                int H) {
  __shared__ __align__(16) char smem[34816];      // 32KB As/Bs|C-tile + 2KB sdred
  ushort_t* As = (ushort_t*)smem;                 // [128*64]
  ushort_t* Bs = (ushort_t*)(smem + 16384);       // [128*64]
  float (*sdred)[2][2] = (float (*)[2][2])(smem + 32768);
  int row0 = blockIdx.x * 128;
  int col0 = blockIdx.y * 128;
  int t = threadIdx.x;
  int lane = t & 63, w = t >> 6;
  int wr = w >> 1, wc = w & 1;
  int r = lane & 15, kg = lane >> 4;

  f32x4 acc[4][4];
#pragma unroll
  for (int m = 0; m < 4; ++m)
#pragma unroll
    for (int n = 0; n < 4; ++n) acc[m][n] = (f32x4){0.f, 0.f, 0.f, 0.f};

  for (int k0 = 0; k0 < K; k0 += 64) {
    __syncthreads();
#pragma unroll
    for (int i = 0; i < 4; ++i) {
      int c = w * 4 + i;                 // 1KB chunk id (16 per tile)
      int b = c * 1024 + lane * 16;      // linear LDS byte this lane fills
      int row = b >> 7;
      int ks = ((b >> 4) & 7) ^ (row & 7);   // inverse swizzle on source
      const ushort_t* ga = A + (size_t)(row0 + row) * K + k0 + ks * 8;
      if (row0 + row < M) gload16(ga, &As[c * 512]);
      const ushort_t* gb = Bt + (size_t)(col0 + row) * K + k0 + ks * 8;
      gload16(gb, &Bs[c * 512]);
    }
    __syncthreads();

#pragma unroll
    for (int kk = 0; kk < 2; ++kk) {
      frag_ab af[4], bf[4];
#pragma unroll
      for (int m = 0; m < 4; ++m) {
        int row = wr * 64 + m * 16 + r;
        int byte = row * 128 + ((kk * 64 + kg * 16) ^ ((row & 7) << 4));
        af[m] = *(const frag_ab*)((const char*)As + byte);
      }
#pragma unroll
      for (int n = 0; n < 4; ++n) {
        int row = wc * 64 + n * 16 + r;
        int byte = row * 128 + ((kk * 64 + kg * 16) ^ ((row & 7) << 4));
        bf[n] = *(const frag_ab*)((const char*)Bs + byte);
      }
#pragma unroll
      for (int m = 0; m < 4; ++m)
#pragma unroll
        for (int n = 0; n < 4; ++n)
          acc[m][n] = __builtin_amdgcn_mfma_f32_16x16x32_bf16(af[m], bf[n], acc[m][n], 0, 0, 0);
    }
  }

  int head = blockIdx.y;
  float as_[4], ad_[4];
#pragma unroll
  for (int n = 0; n < 4; ++n) {
    int cloc = wc * 64 + n * 16 + r;
    as_[n] = a_src[head * 128 + cloc];
    ad_[n] = a_dst[head * 128 + cloc];
  }

  __syncthreads();                      // all ds_reads done; reuse As/Bs as C tile
  char* ct = smem;

#pragma unroll
  for (int m = 0; m < 4; ++m) {
#pragma unroll
    for (int q = 0; q < 4; ++q) {
      int row_loc = wr * 64 + m * 16 + kg * 4 + q;
      int grow = row0 + row_loc;
      float ps = 0.f, pd = 0.f;
      int sw = ((row_loc >> 2) & 3) << 5;    // kg-dependent bank shift
      if (grow < M) {
#pragma unroll
        for (int n = 0; n < 4; ++n) {
          int col = wc * 64 + n * 16 + r;
          float val = acc[m][n][q];
          ps += val * as_[n]; pd += val * ad_[n];
          *(ushort_t*)(ct + row_loc * 256 + ((col * 2) ^ sw)) = f2b(val);
        }
      }
#pragma unroll
      for (int o = 1; o < 16; o <<= 1) {
        ps += __shfl_xor(ps, o);
        pd += __shfl_xor(pd, o);
      }
      if (r == 0) { sdred[row_loc][wc][0] = ps; sdred[row_loc][wc][1] = pd; }
    }
  }
  __syncthreads();

  // coalesced C stores: 8 threads/row, 32B each, 4 passes
  {
    int sub = t & 7;
    int rbase = t >> 3;                 // 0..31
#pragma unroll
    for (int p = 0; p < 4; ++p) {
      int row = p * 32 + rbase;
      int grow = row0 + row;
      if (grow < M) {
        int sw = ((row >> 2) & 3) << 5;
        uint4 v0 = *(const uint4*)(ct + row * 256 + ((sub * 32) ^ sw));
        uint4 v1 = *(const uint4*)(ct + row * 256 + (((sub * 32) ^ sw) + 16));
        *(uint4*)&C[(size_t)grow * Nc + col0 + sub * 16] = v0;
        *(uint4*)&C[(size_t)grow * Nc + col0 + sub * 16 + 8] = v1;
      }
    }
  }

  // s/d final store
  {
    int row = t >> 1, which = t & 1;
    int grow = row0 + row;
    if (grow < M) {
      float v = sdred[row][0][which] + sdred[row][1][which];
      float* dst = which ? dbuf : sbuf;
      dst[(size_t)grow * H + head] = v;
    }
  }
}

// ------------- fused softmax + alpha + gather, H=2, bf16 out
// TWO nodes per wave (CSR-adjacent): both nodes' 10-deep prefetches issued
// before both softmaxes -> 20 loads in flight per wave (2x round-8 MLP).
// Tail loops bounds-checked (pa=0 for ep>=deg). Fallback if either deg>64.
__global__ __launch_bounds__(256) void k_agg2(const ushort_t* __restrict__ h2,
                                              const float* __restrict__ s,
                                              const float* __restrict__ dv,
                                              const int* __restrict__ row_ptr,
                                              const int* __restrict__ col_src,
                                              const float* __restrict__ bias,
                                              uint4* __restrict__ out) {
  int wid = threadIdx.x >> 6, l = threadIdx.x & 63;
  int pr = blockIdx.x * 4 + wid;
  int n0 = pr * 2;
  if (n0 >= NN) return;
  int n1 = n0 + 1;                      // NN even -> always valid
  int hw = l >> 5, lh = l & 31, hd = lh >> 4;
  const char* hb = (const char*)h2 + lh * 16;

  int beg0 = row_ptr[n0], end0 = row_ptr[n0 + 1];
  int end1 = row_ptr[n1 + 1];
  int beg1 = end0;                      // CSR contiguity
  int deg0 = end0 - beg0, deg1 = end1 - beg1;
  float2 q0 = ((const float2*)dv)[n0];
  float2 q1 = ((const float2*)dv)[n1];

  if (deg0 <= 64 && deg1 <= 64) {
    int s0v = 0, s1v = 0;
    float x00 = -1e30f, x01 = -1e30f, x10 = -1e30f, x11 = -1e30f;
    if (l < deg0) {
      s0v = col_src[beg0 + l];
      float2 sv = ((const float2*)s)[s0v];
      x00 = sv.x + q0.x; x00 = x00 > 0.f ? x00 : 0.2f * x00;
      x01 = sv.y + q0.y; x01 = x01 > 0.f ? x01 : 0.2f * x01;
    }
    if (l < deg1) {
      s1v = col_src[beg1 + l];
      float2 sv = ((const float2*)s)[s1v];
      x10 = sv.x + q1.x; x10 = x10 > 0.f ? x10 : 0.2f * x10;
      x11 = sv.y + q1.y; x11 = x11 > 0.f ? x11 : 0.2f * x11;
    }
    int o0 = s0v << 9, o1 = s1v << 9;

    // ---- issue BOTH nodes' prefetches (edges 0..19 each)
    uint4 P0[10], P1[10];
#pragma unroll
    for (int i = 0; i < 10; ++i)
      P0[i] = *(const uint4*)(hb + __shfl(o0, 2 * i + hw));
#pragma unroll
    for (int i = 0; i < 10; ++i)
      P1[i] = *(const uint4*)(hb + __shfl(o1, 2 * i + hw));

    // ---- both softmaxes (latency cover for 20 outstanding loads)
    float m00 = x00, m01 = x01, m10 = x10, m11 = x11;
#pragma unroll
    for (int o = 1; o < 64; o <<= 1) {
      m00 = fmaxf(m00, __shfl_xor(m00, o));
      m01 = fmaxf(m01, __shfl_xor(m01, o));
      m10 = fmaxf(m10, __shfl_xor(m10, o));
      m11 = fmaxf(m11, __shfl_xor(m11, o));
    }
    float p00 = __expf(x00 - m00), p01 = __expf(x01 - m01);
    float p10 = __expf(x10 - m10), p11 = __expf(x11 - m11);
    float d00 = p00, d01 = p01, d10 = p10, d11 = p11;
#pragma unroll
    for (int o = 1; o < 64; o <<= 1) {
      d00 += __shfl_xor(d00, o); d01 += __shfl_xor(d01, o);
      d10 += __shfl_xor(d10, o); d11 += __shfl_xor(d11, o);
    }

    // ---- node0 consume
    f32x2 A0 = {0.f, 0.f}, A1 = {0.f, 0.f}, A2 = {0.f, 0.f}, A3 = {0.f, 0.f};
#pragma unroll
    for (int i = 0; i < 10; ++i) {
      int ep = 2 * i + hw;
      float pa0 = __shfl(p00, ep), pa1 = __shfl(p01, ep);
      float pa = hd ? pa1 : pa0;
      f32x2 pp = {pa, pa};
      A0 = __builtin_elementwise_fma(unp2(P0[i].x), pp, A0);
      A1 = __builtin_elementwise_fma(unp2(P0[i].y), pp, A1);
      A2 = __builtin_elementwise_fma(unp2(P0[i].z), pp, A2);
      A3 = __builtin_elementwise_fma(unp2(P0[i].w), pp, A3);
    }
    for (int e = 20; e < deg0; e += 8) {
#pragma unroll
      for (int i = 0; i < 4; ++i) {
        int ep = e + 2 * i + hw;
        int off = __shfl(o0, ep & 63);
        float pa0 = __shfl(p00, ep & 63), pa1 = __shfl(p01, ep & 63);
        float pa = hd ? pa1 : pa0;
        if (ep >= deg0) pa = 0.f;
        uint4 v = *(const uint4*)(hb + off);
        f32x2 pp = {pa, pa};
        A0 = __builtin_elementwise_fma(unp2(v.x), pp, A0);
        A1 = __builtin_elementwise_fma(unp2(v.y), pp, A1);
        A2 = __builtin_elementwise_fma(unp2(v.z), pp, A2);
        A3 = __builtin_elementwise_fma(unp2(v.w), pp, A3);
      }
    }
    A0.x += __shfl_xor(A0.x, 32); A0.y += __shfl_xor(A0.y, 32);
    A1.x += __shfl_xor(A1.x, 32); A1.y += __shfl_xor(A1.y, 32);
    A2.x += __shfl_xor(A2.x, 32); A2.y += __shfl_xor(A2.y, 32);
    A3.x += __shfl_xor(A3.x, 32); A3.y += __shfl_xor(A3.y, 32);
    if (hw == 0) {
      float inv = 1.f / (hd ? d01 : d00);
      float4 b0 = ((const float4*)bias)[2 * lh];
      float4 b1 = ((const float4*)bias)[2 * lh + 1];
      uint4 ov;
      ov.x = (uint_t)f2b(A0.x * inv + b0.x) | ((uint_t)f2b(A0.y * inv + b0.y) << 16);
      ov.y = (uint_t)f2b(A1.x * inv + b0.z) | ((uint_t)f2b(A1.y * inv + b0.w) << 16);
      ov.z = (uint_t)f2b(A2.x * inv + b1.x) | ((uint_t)f2b(A2.y * inv + b1.y) << 16);
      ov.w = (uint_t)f2b(A3.x * inv + b1.z) | ((uint_t)f2b(A3.y * inv + b1.w) << 16);
      out[(size_t)n0 * 32 + lh] = ov;
    }

    // ---- node1 consume
    A0 = (f32x2){0.f, 0.f}; A1 = (f32x2){0.f, 0.f};
    A2 = (f32x2){0.f, 0.f}; A3 = (f32x2){0.f, 0.f};
#pragma unroll
    for (int i = 0; i < 10; ++i) {
      int ep = 2 * i + hw;
      float pa0 = __shfl(p10, ep), pa1 = __shfl(p11, ep);
      float pa = hd ? pa1 : pa0;
      f32x2 pp = {pa, pa};
      A0 = __builtin_elementwise_fma(unp2(P1[i].x), pp, A0);
      A1 = __builtin_elementwise_fma(unp2(P1[i].y), pp, A1);
      A2 = __builtin_elementwise_fma(unp2(P1[i].z), pp, A2);
      A3 = __builtin_elementwise_fma(unp2(P1[i].w), pp, A3);
    }
    for (int e = 20; e < deg1; e += 8) {
#pragma unroll
      for (int i = 0; i < 4; ++i) {
        int ep = e + 2 * i + hw;
        int off = __shfl(o1, ep & 63);
        float pa0 = __shfl(p10, ep & 63), pa1 = __shfl(p11, ep & 63);
        float pa = hd ? pa1 : pa0;
        if (ep >= deg1) pa = 0.f;
        uint4 v = *(const uint4*)(hb + off);
        f32x2 pp = {pa, pa};
        A0 = __builtin_elementwise_fma(unp2(v.x), pp, A0);
        A1 = __builtin_elementwise_fma(unp2(v.y), pp, A1);
        A2 = __builtin_elementwise_fma(unp2(v.z), pp, A2);
        A3 = __builtin_elementwise_fma(unp2(v.w), pp, A3);
      }
    }
    A0.x += __shfl_xor(A0.x, 32); A0.y += __shfl_xor(A0.y, 32);
    A1.x += __shfl_xor(A1.x, 32); A1.y += __shfl_xor(A1.y, 32);
    A2.x += __shfl_xor(A2.x, 32); A2.y += __shfl_xor(A2.y, 32);
    A3.x += __shfl_xor(A3.x, 32); A3.y += __shfl_xor(A3.y, 32);
    if (hw == 0) {
      float inv = 1.f / (hd ? d11 : d10);
      float4 b0 = ((const float4*)bias)[2 * lh];
      float4 b1 = ((const float4*)bias)[2 * lh + 1];
      uint4 ov;
      ov.x = (uint_t)f2b(A0.x * inv + b0.x) | ((uint_t)f2b(A0.y * inv + b0.y) << 16);
      ov.y = (uint_t)f2b(A1.x * inv + b0.z) | ((uint_t)f2b(A1.y * inv + b0.w) << 16);
      ov.z = (uint_t)f2b(A2.x * inv + b1.x) | ((uint_t)f2b(A2.y * inv + b1.y) << 16);
      ov.w = (uint_t)f2b(A3.x * inv + b1.z) | ((uint_t)f2b(A3.y * inv + b1.w) << 16);
      out[(size_t)n1 * 32 + lh] = ov;
    }
  } else {
    // fallback (deg>64, ~never for this graph): online softmax + chunked gather
#pragma unroll 1
    for (int which = 0; which < 2; ++which) {
      int n = which ? n1 : n0;
      int beg = which ? beg1 : beg0;
      int end = which ? end1 : end0;
      float dn0 = which ? q1.x : q0.x, dn1 = which ? q1.y : q0.y;
      f32x2 A0 = {0.f, 0.f}, A1 = {0.f, 0.f}, A2 = {0.f, 0.f}, A3 = {0.f, 0.f};
      float m0 = -1e30f, m1 = -1e30f, d0 = 0.f, d1 = 0.f;
      for (int e = beg + l; e < end; e += 64) {
        int src = col_src[e];
        float2 sv = ((const float2*)s)[src];
        float x0 = sv.x + dn0; x0 = x0 > 0.f ? x0 : 0.2f * x0;
        if (x0 > m0) { d0 = d0 * __expf(m0 - x0) + 1.f; m0 = x0; } else d0 += __expf(x0 - m0);
        float x1 = sv.y + dn1; x1 = x1 > 0.f ? x1 : 0.2f * x1;
        if (x1 > m1) { d1 = d1 * __expf(m1 - x1) + 1.f; m1 = x1; } else d1 += __expf(x1 - m1);
      }
#pragma unroll
      for (int o = 1; o < 64; o <<= 1) {
        float mo = __shfl_xor(m0, o), dno = __shfl_xor(d0, o);
        float M2 = fmaxf(m0, mo);
        d0 = d0 * __expf(m0 - M2) + dno * __expf(mo - M2);
        m0 = M2;
        mo = __shfl_xor(m1, o); dno = __shfl_xor(d1, o);
        M2 = fmaxf(m1, mo);
        d1 = d1 * __expf(m1 - M2) + dno * __expf(mo - M2);
        m1 = M2;
      }
      for (int c = beg; c < end; c += 64) {
        int cnt = min(64, end - c);
        int srcv = 0; float x0 = -1e30f, x1 = -1e30f;
        if (l < cnt) {
          srcv = col_src[c + l];
          float2 sv = ((const float2*)s)[srcv];
          x0 = sv.x + dn0; x0 = x0 > 0.f ? x0 : 0.2f * x0;
          x1 = sv.y + dn1; x1 = x1 > 0.f ? x1 : 0.2f * x1;
        }
        float p0 = __expf(x0 - m0), p1 = __expf(x1 - m1);
        int offv = srcv << 9;
        for (int e = 0; e < cnt; e += 8) {
#pragma unroll
          for (int i = 0; i < 4; ++i) {
            int ep = e + 2 * i + hw;
            int off = __shfl(offv, ep & 63);
            float pa0 = __shfl(p0, ep & 63), pa1 = __shfl(p1, ep & 63);
            float pa = hd ? pa1 : pa0;
            if (ep >= cnt) pa = 0.f;
            uint4 v = *(const uint4*)(hb + off);
            f32x2 pp = {pa, pa};
            A0 = __builtin_elementwise_fma(unp2(v.x), pp, A0);
            A1 = __builtin_elementwise_fma(unp2(v.y), pp, A1);
            A2 = __builtin_elementwise_fma(unp2(v.z), pp, A2);
            A3 = __builtin_elementwise_fma(unp2(v.w), pp, A3);
          }
        }
      }
      A0.x += __shfl_xor(A0.x, 32); A0.y += __shfl_xor(A0.y, 32);
      A1.x += __shfl_xor(A1.x, 32); A1.y += __shfl_xor(A1.y, 32);
      A2.x += __shfl_xor(A2.x, 32); A2.y += __shfl_xor(A2.y, 32);
      A3.x += __shfl_xor(A3.x, 32); A3.y += __shfl_xor(A3.y, 32);
      if (hw == 0) {
        float inv = 1.f / (hd ? d1 : d0);
        float4 b0 = ((const float4*)bias)[2 * lh];
        float4 b1 = ((const float4*)bias)[2 * lh + 1];
        uint4 ov;
        ov.x = (uint_t)f2b(A0.x * inv + b0.x) | ((uint_t)f2b(A0.y * inv + b0.y) << 16);
        ov.y = (uint_t)f2b(A1.x * inv + b0.z) | ((uint_t)f2b(A1.y * inv + b0.w) << 16);
        ov.z = (uint_t)f2b(A2.x * inv + b1.x) | ((uint_t)f2b(A2.y * inv + b1.y) << 16);
        ov.w = (uint_t)f2b(A3.x * inv + b1.z) | ((uint_t)f2b(A3.y * inv + b1.w) << 16);
        out[(size_t)n * 32 + lh] = ov;
      }
    }
  }
}

// ------------- fused softmax + alpha + gather, H=1, f32 out  (round-8 version)
__global__ __launch_bounds__(256) void k_agg1(const ushort_t* __restrict__ h2,
                                              const float* __restrict__ s,
                                              const float* __restrict__ dv,
                                              const int* __restrict__ row_ptr,
                                              const int* __restrict__ col_src,
                                              const float* __restrict__ bias,
                                              float* __restrict__ out) {
  int wid = threadIdx.x >> 6, l = threadIdx.x & 63;
  int n = blockIdx.x * 4 + wid;
  if (n >= NN) return;
  int beg = row_ptr[n], end = row_ptr[n + 1];
  int deg = end - beg;
  float dn0 = dv[n];
  int hw = l >> 4, lh = l & 15;
  const char* hb = (const char*)h2 + lh * 16;

  f32x2 A0 = {0.f, 0.f}, A1 = {0.f, 0.f}, A2 = {0.f, 0.f}, A3 = {0.f, 0.f};
  float d0;

  if (deg <= 64) {
    int srcv = 0; float x0 = -1e30f;
    if (l < deg) {
      srcv = col_src[beg + l];
      x0 = s[srcv] + dn0; x0 = x0 > 0.f ? x0 : 0.2f * x0;
    }
    int offv = srcv << 8;               // 256B rows

    uint4 P[6];
#pragma unroll
    for (int i = 0; i < 6; ++i)
      P[i] = *(const uint4*)(hb + __shfl(offv, 4 * i + hw));

    float m0 = x0;
#pragma unroll
    for (int o = 1; o < 64; o <<= 1) m0 = fmaxf(m0, __shfl_xor(m0, o));
    float p0 = __expf(x0 - m0);
    d0 = p0;
#pragma unroll
    for (int o = 1; o < 64; o <<= 1) d0 += __shfl_xor(d0, o);

#pragma unroll
    for (int i = 0; i < 6; ++i) {
      float pa = __shfl(p0, 4 * i + hw);
      f32x2 pp = {pa, pa};
      A0 = __builtin_elementwise_fma(unp2(P[i].x), pp, A0);
      A1 = __builtin_elementwise_fma(unp2(P[i].y), pp, A1);
      A2 = __builtin_elementwise_fma(unp2(P[i].z), pp, A2);
      A3 = __builtin_elementwise_fma(unp2(P[i].w), pp, A3);
    }
    for (int e = 24; e < deg; e += 8) {
#pragma unroll
      for (int i = 0; i < 2; ++i) {
        int ep = e + 4 * i + hw;
        int off = __shfl(offv, ep);
        float pa = __shfl(p0, ep);
        uint4 v = *(const uint4*)(hb + off);
        f32x2 pp = {pa, pa};
        A0 = __builtin_elementwise_fma(unp2(v.x), pp, A0);
        A1 = __builtin_elementwise_fma(unp2(v.y), pp, A1);
        A2 = __builtin_elementwise_fma(unp2(v.z), pp, A2);
        A3 = __builtin_elementwise_fma(unp2(v.w), pp, A3);
      }
    }
  } else {
    float m0 = -1e30f;
    d0 = 0.f;
    for (int e = beg + l; e < end; e += 64) {
      float x0 = s[col_src[e]] + dn0;
      x0 = x0 > 0.f ? x0 : 0.2f * x0;
      if (x0 > m0) { d0 = d0 * __expf(m0 - x0) + 1.f; m0 = x0; } else d0 += __expf(x0 - m0);
    }
#pragma unroll
    for (int o = 1; o < 64; o <<= 1) {
      float mo = __shfl_xor(m0, o), dno = __shfl_xor(d0, o);
      float M2 = fmaxf(m0, mo);
      d0 = d0 * __expf(m0 - M2) + dno * __expf(mo - M2);
      m0 = M2;
    }
    for (int c = beg; c < end; c += 64) {
      int cnt = min(64, end - c);
      int srcv = 0; float x0 = -1e30f;
      if (l < cnt) {
        srcv = col_src[c + l];
        x0 = s[srcv] + dn0; x0 = x0 > 0.f ? x0 : 0.2f * x0;
      }
      float p0 = __expf(x0 - m0);
      int offv = srcv << 8;
      for (int e = 0; e < cnt; e += 8) {
#pragma unroll
        for (int i = 0; i < 2; ++i) {
          int ep = e + 4 * i + hw;
          int off = __shfl(offv, ep & 63);
          float pa = __shfl(p0, ep & 63);
          if (ep >= cnt) pa = 0.f;
          uint4 v = *(const uint4*)(hb + off);
          f32x2 pp = {pa, pa};
          A0 = __builtin_elementwise_fma(unp2(v.x), pp, A0);
          A1 = __builtin_elementwise_fma(unp2(v.y), pp, A1);
          A2 = __builtin_elementwise_fma(unp2(v.z), pp, A2);
          A3 = __builtin_elementwise_fma(unp2(v.w), pp, A3);
        }
      }
    }
  }

#pragma unroll
  for (int o = 16; o < 64; o <<= 1) {
    A0.x += __shfl_xor(A0.x, o); A0.y += __shfl_xor(A0.y, o);
    A1.x += __shfl_xor(A1.x, o); A1.y += __shfl_xor(A1.y, o);
    A2.x += __shfl_xor(A2.x, o); A2.y += __shfl_xor(A2.y, o);
    A3.x += __shfl_xor(A3.x, o); A3.y += __shfl_xor(A3.y, o);
  }
  if (hw == 0) {
    float inv = 1.f / d0;
    float4 b0 = ((const float4*)bias)[2 * lh];
    float4 b1 = ((const float4*)bias)[2 * lh + 1];
    float4 o0 = make_float4(A0.x * inv + b0.x, A0.y * inv + b0.y,
                            A1.x * inv + b0.z, A1.y * inv + b0.w);
    float4 o1 = make_float4(A2.x * inv + b1.x, A2.y * inv + b1.y,
                            A3.x * inv + b1.z, A3.y * inv + b1.w);
    ((float4*)out)[(size_t)n * 32 + 2 * lh] = o0;
    ((float4*)out)[(size_t)n * 32 + 2 * lh + 1] = o1;
  }
}

// ---------------------------------------------------------------- launch
extern "C" void kernel_launch(void* const* d_in, const int* in_sizes, int n_in,
                              void* d_out, int out_size, void* d_ws, size_t ws_size,
                              hipStream_t stream) {
  const float* x     = (const float*)d_in[0];
  const int*   edge  = (const int*)d_in[1];
  const float* fc_w  = (const float*)d_in[2];
  const float* fc_b  = (const float*)d_in[3];
  const float* W1    = (const float*)d_in[4];
  const float* asrc1 = (const float*)d_in[5];
  const float* adst1 = (const float*)d_in[6];
  const float* b1    = (const float*)d_in[7];
  const float* Wm    = (const float*)d_in[8];
  const float* asrcm = (const float*)d_in[9];
  const float* adstm = (const float*)d_in[10];
  const float* bm    = (const float*)d_in[11];
  const float* W6    = (const float*)d_in[12];
  const float* asrc6 = (const float*)d_in[13];
  const float* adst6 = (const float*)d_in[14];
  const float* b6    = (const float*)d_in[15];

  char* w = (char*)d_ws;
  size_t off = 0;
  auto carve = [&](size_t bytes) -> char* {
    char* p = w + off;
    off = (off + bytes + 255) & ~(size_t)255;
    return p;
  };
  ushort_t* feat0 = (ushort_t*)carve((size_t)NN * 256 * 2);
  ushort_t* feat1 = (ushort_t*)carve((size_t)NN * 256 * 2);
  ushort_t* hbuf  = (ushort_t*)carve((size_t)NN * 256 * 2);
  float* sbuf   = (float*)carve((size_t)NN * 2 * 4);
  float* dbuf   = (float*)carve((size_t)NN * 2 * 4);
  ushort_t* fcWt = (ushort_t*)carve((size_t)128 * 64 * 2);
  ushort_t* W1t  = (ushort_t*)carve((size_t)256 * 128 * 2);
  ushort_t* Wmt  = (ushort_t*)carve((size_t)4 * 256 * 256 * 2);
  ushort_t* W6t  = (ushort_t*)carve((size_t)128 * 256 * 2);
  int* counts   = (int*)carve((size_t)NN * 4);
  int* row_ptr  = (int*)carve((size_t)(NN + 1) * 4);
  int* cursor   = (int*)carve((size_t)NN * 4);
  int* col_src  = (int*)carve((size_t)ET * 4);
  int* scn      = (int*)carve((size_t)NN * 4);
  int* bsum     = (int*)carve((size_t)64 * 4);
  int* boff     = (int*)carve((size_t)64 * 4);
  (void)ws_size;

  // weight prep
  k_prep_w<<<(335872 + 255) / 256, 256, 0, stream>>>(fc_w, W1, Wm, W6, fcWt, W1t, Wmt, W6t);

  // CSR build
  hipMemsetAsync(counts, 0, (size_t)NN * 4, stream);
  int eb = (ET + 255) / 256;
  const int NB = (NN + 1023) / 1024;   // 49
  k_count<<<eb, 256, 0, stream>>>(edge, counts);
  k_scan1<<<NB, 1024, 0, stream>>>(counts, scn, bsum);
  k_scan2<<<1, 64, 0, stream>>>(bsum, boff);
  k_scan3<<<NB, 1024, 0, stream>>>(scn, boff, row_ptr, cursor);
  k_fill<<<eb, 256, 0, stream>>>(edge, cursor, col_src);

  dim3 g1((NN + 127) / 128, 1), g2((NN + 127) / 128, 2);
  int ab = (NN + 3) / 4;
  int ab2 = (NN / 2 + 3) / 4;          // 2 nodes per wave

  auto gat = [&](const ushort_t* in, int K, const ushort_t* Wt, const float* a_s,
                 const float* a_d, const float* bias, void* outp, int H) {
    k_gemm64<<<(H == 2 ? g2 : g1), 256, 0, stream>>>(
        in, Wt, hbuf, NN, K, H * 128, a_s, a_d, sbuf, dbuf, H);
    if (H == 2)
      k_agg2<<<ab2, 256, 0, stream>>>(hbuf, sbuf, dbuf, row_ptr, col_src, bias, (uint4*)outp);
    else
      k_agg1<<<ab, 256, 0, stream>>>(hbuf, sbuf, dbuf, row_ptr, col_src, bias, (float*)outp);
  };

  // fc: relu(x @ fc_w + fc_b) -> feat0 bf16 [N,128]
  k_gemm_f32<<<g1, 256, 0, stream>>>(x, fcWt, feat0, NN, 64, 128, fc_b);

  // layer 1: 128 -> 2x128 concat
  gat(feat0, 128, W1t, asrc1, adst1, b1, feat1, 2);

  // middle layers: 256 -> 2x128 concat (ping-pong)
  const ushort_t* cur = feat1;
  ushort_t* nxt = feat0;
  for (int i = 0; i < 4; ++i) {
    gat(cur, 256, Wmt + (size_t)i * 256 * 256, asrcm + (size_t)i * 2 * 128,
        adstm + (size_t)i * 2 * 128, bm + (size_t)i * 256, nxt, 2);
    const ushort_t* tmp = cur;
    cur = nxt;
    nxt = (ushort_t*)tmp;
  }

  // layer 6: 256 -> 1x128, f32 out to d_out
  gat(cur, 256, W6t, asrc6, adst6, b6, d_out, 1);
}

// Round 16
// 560.773 us; speedup vs baseline: 1.0609x; 1.0609x over previous
//
#include <hip/hip_runtime.h>
#include <cstdint>
#include <cstddef>

#define NN 50000
#define EE 800000
#define ET 850000   // EE + NN self loops

typedef unsigned short ushort_t;
typedef unsigned int uint_t;
using frag_ab = __attribute__((ext_vector_type(8))) short;   // 8 bf16
using f32x4   = __attribute__((ext_vector_type(4))) float;
using f32x2   = __attribute__((ext_vector_type(2))) float;

__device__ inline ushort_t f2b(float x) {
  union { float f; unsigned int u; } c; c.f = x;
  unsigned int u = c.u;
  u += 0x7fffu + ((u >> 16) & 1u);   // round-to-nearest-even
  return (ushort_t)(u >> 16);
}
__device__ inline float b2f(uint_t u) {
  union { unsigned int u; float f; } c; c.u = u << 16;
  return c.f;
}
// unpack uint (2 bf16) -> f32x2 {lo, hi}
__device__ inline f32x2 unp2(uint_t u) {
  union { uint_t u; float f; } lo, hi;
  lo.u = u << 16; hi.u = u & 0xffff0000u;
  f32x2 r; r.x = lo.f; r.y = hi.f; return r;
}

// async global->LDS, 16B per lane; LDS dest = wave-uniform base + lane*16
__device__ inline void gload16(const ushort_t* g, ushort_t* l) {
  __builtin_amdgcn_global_load_lds(
      (const __attribute__((address_space(1))) unsigned int*)g,
      (__attribute__((address_space(3))) unsigned int*)l, 16, 0, 0);
}

// ---------------------------------------------------------------- CSR build
__global__ __launch_bounds__(256) void k_count(const int* __restrict__ edge,
                                               int* __restrict__ counts) {
  int e = blockIdx.x * 256 + threadIdx.x;
  if (e >= ET) return;
  int dd = (e < EE) ? edge[EE + e] : (e - EE);
  atomicAdd(&counts[dd], 1);
}

__global__ __launch_bounds__(1024) void k_scan1(const int* __restrict__ counts,
                                                int* __restrict__ scn,
                                                int* __restrict__ bsum) {
  __shared__ int tmp[1024];
  int tid = threadIdx.x;
  int idx = blockIdx.x * 1024 + tid;
  int v = (idx < NN) ? counts[idx] : 0;
  tmp[tid] = v;
  __syncthreads();
  for (int o = 1; o < 1024; o <<= 1) {
    int u = (tid >= o) ? tmp[tid - o] : 0;
    __syncthreads();
    tmp[tid] += u;
    __syncthreads();
  }
  if (idx < NN) scn[idx] = tmp[tid] - v;
  if (tid == 1023) bsum[blockIdx.x] = tmp[1023];
}

__global__ __launch_bounds__(64) void k_scan2(const int* __restrict__ bsum,
                                              int* __restrict__ boff) {
  int l = threadIdx.x;
  const int NB = (NN + 1023) / 1024;           // 49
  int v = (l < NB) ? bsum[l] : 0;
  int own = v;
  for (int o = 1; o < 64; o <<= 1) {
    int u = __shfl_up(v, o);
    if (l >= o) v += u;
  }
  if (l < NB) boff[l] = v - own;
}

__global__ __launch_bounds__(1024) void k_scan3(const int* __restrict__ scn,
                                                const int* __restrict__ boff,
                                                int* __restrict__ row_ptr,
                                                int* __restrict__ cursor) {
  int idx = blockIdx.x * 1024 + threadIdx.x;
  if (idx < NN) {
    int v = scn[idx] + boff[blockIdx.x];
    row_ptr[idx] = v;
    cursor[idx] = v;
  }
  if (idx == 0) row_ptr[NN] = ET;
}

__global__ __launch_bounds__(256) void k_fill(const int* __restrict__ edge,
                                              int* __restrict__ cursor,
                                              int* __restrict__ col_src) {
  int e = blockIdx.x * 256 + threadIdx.x;
  if (e >= ET) return;
  int ss, dd;
  if (e < EE) { ss = edge[e]; dd = edge[EE + e]; }
  else        { ss = dd = e - EE; }
  int pos = atomicAdd(&cursor[dd], 1);
  col_src[pos] = ss;
}

// ---------------------------------------------------- weight prep (bf16, [n][k])
__global__ __launch_bounds__(256) void k_prep_w(const float* __restrict__ fc_w,
                                                const float* __restrict__ W1,
                                                const float* __restrict__ Wm,
                                                const float* __restrict__ W6,
                                                ushort_t* __restrict__ fcWt,
                                                ushort_t* __restrict__ W1t,
                                                ushort_t* __restrict__ Wmt,
                                                ushort_t* __restrict__ W6t) {
  int i = blockIdx.x * 256 + threadIdx.x;
  if (i < 128 * 64) { int n = i >> 6, k = i & 63; fcWt[i] = f2b(fc_w[k * 128 + n]); return; }
  i -= 128 * 64;
  if (i < 256 * 128) { int n = i >> 7, k = i & 127; W1t[i] = f2b(W1[k * 256 + n]); return; }
  i -= 256 * 128;
  if (i < 4 * 256 * 256) {
    int l = i >> 16, r2 = i & 65535, n = r2 >> 8, k = r2 & 255;
    Wmt[i] = f2b(Wm[(size_t)l * 65536 + k * 256 + n]); return;
  }
  i -= 4 * 256 * 256;
  if (i < 128 * 256) { int n = i >> 8, k = i & 255; W6t[i] = f2b(W6[k * 128 + n]); return; }
}

// ---------------------------------------------- fc GEMM (f32 input)
__global__ __launch_bounds__(256) void k_gemm_f32(const float* __restrict__ A,
                                                  const ushort_t* __restrict__ Bt,
                                                  ushort_t* __restrict__ C,
                                                  int M, int K, int Nc,
                                                  const float* __restrict__ bias) {
  __shared__ ushort_t As[128 * 40];
  __shared__ ushort_t Bs[128 * 40];
  int row0 = blockIdx.x * 128;
  int col0 = blockIdx.y * 128;
  int t = threadIdx.x;
  int lane = t & 63, w = t >> 6;
  int wr = w >> 1, wc = w & 1;
  int r = lane & 15, kg = lane >> 4;

  f32x4 acc[4][4];
#pragma unroll
  for (int m = 0; m < 4; ++m)
#pragma unroll
    for (int n = 0; n < 4; ++n) acc[m][n] = (f32x4){0.f, 0.f, 0.f, 0.f};

  for (int k0 = 0; k0 < K; k0 += 32) {
    __syncthreads();
#pragma unroll
    for (int rep = 0; rep < 4; ++rep) {
      int c = t + rep * 256;
      int row = c >> 3, kc = c & 7;
      int grow = row0 + row;
      if (grow < M) {
        float4 v = *(const float4*)&A[(size_t)grow * K + k0 + kc * 4];
        ushort4 u;
        u.x = f2b(v.x); u.y = f2b(v.y); u.z = f2b(v.z); u.w = f2b(v.w);
        *(ushort4*)&As[row * 40 + kc * 4] = u;
      }
    }
#pragma unroll
    for (int rep = 0; rep < 2; ++rep) {
      int c = t + rep * 256;
      int row = c >> 2, kc = c & 3;
      uint4 v = *(const uint4*)&Bt[(size_t)(col0 + row) * K + k0 + kc * 8];
      *(uint4*)&Bs[row * 40 + kc * 8] = v;
    }
    __syncthreads();

    frag_ab a[4], b[4];
#pragma unroll
    for (int m = 0; m < 4; ++m)
      a[m] = *(const frag_ab*)&As[(wr * 64 + m * 16 + r) * 40 + kg * 8];
#pragma unroll
    for (int n = 0; n < 4; ++n)
      b[n] = *(const frag_ab*)&Bs[(wc * 64 + n * 16 + r) * 40 + kg * 8];
#pragma unroll
    for (int m = 0; m < 4; ++m)
#pragma unroll
      for (int n = 0; n < 4; ++n)
        acc[m][n] = __builtin_amdgcn_mfma_f32_16x16x32_bf16(a[m], b[n], acc[m][n], 0, 0, 0);
  }

#pragma unroll
  for (int m = 0; m < 4; ++m) {
    int gr0 = row0 + wr * 64 + m * 16 + kg * 4;
#pragma unroll
    for (int q = 0; q < 4; ++q) {
      int grow = gr0 + q;
      if (grow >= M) continue;
#pragma unroll
      for (int n = 0; n < 4; ++n) {
        int gcol = col0 + wc * 64 + n * 16 + r;
        float val = acc[m][n][q] + bias[gcol];
        val = fmaxf(val, 0.f);
        C[(size_t)grow * Nc + gcol] = f2b(val);
      }
    }
  }
}

// ------------------------------- GAT GEMM: bf16, BK=64, global_load_lds + swizzle
__global__ __launch_bounds__(256) void k_gemm64(const ushort_t* __restrict__ A,
                                                const ushort_t* __restrict__ Bt,
                                                ushort_t* __restrict__ C,
                                                int M, int K, int Nc,
                                                const float* __restrict__ a_src,
                                                const float* __restrict__ a_dst,
                                                float* __restrict__ sbuf,
                                                float* __restrict__ dbuf,
                                                int H) {
  __shared__ ushort_t As[128 * 64];
  __shared__ ushort_t Bs[128 * 64];
  __shared__ float sdred[128][2][2];
  int row0 = blockIdx.x * 128;
  int col0 = blockIdx.y * 128;
  int t = threadIdx.x;
  int lane = t & 63, w = t >> 6;
  int wr = w >> 1, wc = w & 1;
  int r = lane & 15, kg = lane >> 4;

  f32x4 acc[4][4];
#pragma unroll
  for (int m = 0; m < 4; ++m)
#pragma unroll
    for (int n = 0; n < 4; ++n) acc[m][n] = (f32x4){0.f, 0.f, 0.f, 0.f};

  for (int k0 = 0; k0 < K; k0 += 64) {
    __syncthreads();
#pragma unroll
    for (int i = 0; i < 4; ++i) {
      int c = w * 4 + i;                 // 1KB chunk id (16 per tile)
      int b = c * 1024 + lane * 16;      // linear LDS byte this lane fills
      int row = b >> 7;
      int ks = ((b >> 4) & 7) ^ (row & 7);   // inverse swizzle on source
      const ushort_t* ga = A + (size_t)(row0 + row) * K + k0 + ks * 8;
      if (row0 + row < M) gload16(ga, &As[c * 512]);
      const ushort_t* gb = Bt + (size_t)(col0 + row) * K + k0 + ks * 8;
      gload16(gb, &Bs[c * 512]);
    }
    __syncthreads();

#pragma unroll
    for (int kk = 0; kk < 2; ++kk) {
      frag_ab af[4], bf[4];
#pragma unroll
      for (int m = 0; m < 4; ++m) {
        int row = wr * 64 + m * 16 + r;
        int byte = row * 128 + ((kk * 64 + kg * 16) ^ ((row & 7) << 4));
        af[m] = *(const frag_ab*)((const char*)As + byte);
      }
#pragma unroll
      for (int n = 0; n < 4; ++n) {
        int row = wc * 64 + n * 16 + r;
        int byte = row * 128 + ((kk * 64 + kg * 16) ^ ((row & 7) << 4));
        bf[n] = *(const frag_ab*)((const char*)Bs + byte);
      }
#pragma unroll
      for (int m = 0; m < 4; ++m)
#pragma unroll
        for (int n = 0; n < 4; ++n)
          acc[m][n] = __builtin_amdgcn_mfma_f32_16x16x32_bf16(af[m], bf[n], acc[m][n], 0, 0, 0);
    }
  }

  int head = blockIdx.y;
  float as_[4], ad_[4];
#pragma unroll
  for (int n = 0; n < 4; ++n) {
    int cloc = wc * 64 + n * 16 + r;
    as_[n] = a_src[head * 128 + cloc];
    ad_[n] = a_dst[head * 128 + cloc];
  }

#pragma unroll
  for (int m = 0; m < 4; ++m) {
    int gr0 = row0 + wr * 64 + m * 16 + kg * 4;
#pragma unroll
    for (int q = 0; q < 4; ++q) {
      int grow = gr0 + q;
      float ps = 0.f, pd = 0.f;
      if (grow < M) {
#pragma unroll
        for (int n = 0; n < 4; ++n) {
          int gcol = col0 + wc * 64 + n * 16 + r;
          float val = acc[m][n][q];
          ps += val * as_[n]; pd += val * ad_[n];
          C[(size_t)grow * Nc + gcol] = f2b(val);
        }
      }
#pragma unroll
      for (int o = 1; o < 16; o <<= 1) {
        ps += __shfl_xor(ps, o);
        pd += __shfl_xor(pd, o);
      }
      int row_loc = wr * 64 + m * 16 + kg * 4 + q;
      if (r == 0) { sdred[row_loc][wc][0] = ps; sdred[row_loc][wc][1] = pd; }
    }
  }
  __syncthreads();
  int row = t >> 1, which = t & 1;
  int grow = row0 + row;
  if (grow < M) {
    float v = sdred[row][0][which] + sdred[row][1][which];
    float* dst = which ? dbuf : sbuf;
    dst[(size_t)grow * H + head] = v;
  }
}

// ------------- fused softmax + alpha + gather, H=2, bf16 out
// 12 prefetch gathers issued BEFORE the softmax trees (T14 issue-early);
// softmax VALU hides gather latency; idle lanes -> alpha=0, predicate-free.
__global__ __launch_bounds__(256) void k_agg2(const ushort_t* __restrict__ h2,
                                              const float* __restrict__ s,
                                              const float* __restrict__ dv,
                                              const int* __restrict__ row_ptr,
                                              const int* __restrict__ col_src,
                                              const float* __restrict__ bias,
                                              uint4* __restrict__ out) {
  int wid = threadIdx.x >> 6, l = threadIdx.x & 63;
  int n = blockIdx.x * 4 + wid;
  if (n >= NN) return;
  int beg = row_ptr[n], end = row_ptr[n + 1];
  int deg = end - beg;
  float2 tdn = ((const float2*)dv)[n];
  float dn0 = tdn.x, dn1 = tdn.y;
  int hw = l >> 5, lh = l & 31, hd = lh >> 4;
  const char* hb = (const char*)h2 + lh * 16;

  f32x2 A0 = {0.f, 0.f}, A1 = {0.f, 0.f}, A2 = {0.f, 0.f}, A3 = {0.f, 0.f};
  float d0, d1;

  if (deg <= 64) {
    int srcv = 0; float x0 = -1e30f, x1 = -1e30f;
    if (l < deg) {
      srcv = col_src[beg + l];
      float2 sv = ((const float2*)s)[srcv];
      x0 = sv.x + dn0; x0 = x0 > 0.f ? x0 : 0.2f * x0;
      x1 = sv.y + dn1; x1 = x1 > 0.f ? x1 : 0.2f * x1;
    }
    int offv = srcv << 9;               // byte offset (512B rows)

    uint4 P[12];
#pragma unroll
    for (int i = 0; i < 12; ++i)
      P[i] = *(const uint4*)(hb + __shfl(offv, 2 * i + hw));

    float m0 = x0, m1 = x1;
#pragma unroll
    for (int o = 1; o < 64; o <<= 1) {
      m0 = fmaxf(m0, __shfl_xor(m0, o));
      m1 = fmaxf(m1, __shfl_xor(m1, o));
    }
    float p0 = __expf(x0 - m0), p1 = __expf(x1 - m1);
    d0 = p0; d1 = p1;
#pragma unroll
    for (int o = 1; o < 64; o <<= 1) {
      d0 += __shfl_xor(d0, o);
      d1 += __shfl_xor(d1, o);
    }

#pragma unroll
    for (int i = 0; i < 12; ++i) {
      int ep = 2 * i + hw;
      float pa0 = __shfl(p0, ep);
      float pa1 = __shfl(p1, ep);
      float pa = hd ? pa1 : pa0;
      f32x2 pp = {pa, pa};
      A0 = __builtin_elementwise_fma(unp2(P[i].x), pp, A0);
      A1 = __builtin_elementwise_fma(unp2(P[i].y), pp, A1);
      A2 = __builtin_elementwise_fma(unp2(P[i].z), pp, A2);
      A3 = __builtin_elementwise_fma(unp2(P[i].w), pp, A3);
    }
    for (int e = 24; e < deg; e += 8) {
#pragma unroll
      for (int i = 0; i < 4; ++i) {
        int ep = e + 2 * i + hw;
        int off = __shfl(offv, ep);
        float pa0 = __shfl(p0, ep);
        float pa1 = __shfl(p1, ep);
        float pa = hd ? pa1 : pa0;
        uint4 v = *(const uint4*)(hb + off);
        f32x2 pp = {pa, pa};
        A0 = __builtin_elementwise_fma(unp2(v.x), pp, A0);
        A1 = __builtin_elementwise_fma(unp2(v.y), pp, A1);
        A2 = __builtin_elementwise_fma(unp2(v.z), pp, A2);
        A3 = __builtin_elementwise_fma(unp2(v.w), pp, A3);
      }
    }
  } else {
    float m0 = -1e30f, m1 = -1e30f;
    d0 = 0.f; d1 = 0.f;
    for (int e = beg + l; e < end; e += 64) {
      int src = col_src[e];
      float2 sv = ((const float2*)s)[src];
      float x0 = sv.x + dn0; x0 = x0 > 0.f ? x0 : 0.2f * x0;
      if (x0 > m0) { d0 = d0 * __expf(m0 - x0) + 1.f; m0 = x0; } else d0 += __expf(x0 - m0);
      float x1 = sv.y + dn1; x1 = x1 > 0.f ? x1 : 0.2f * x1;
      if (x1 > m1) { d1 = d1 * __expf(m1 - x1) + 1.f; m1 = x1; } else d1 += __expf(x1 - m1);
    }
#pragma unroll
    for (int o = 1; o < 64; o <<= 1) {
      float mo = __shfl_xor(m0, o), dno = __shfl_xor(d0, o);
      float M2 = fmaxf(m0, mo);
      d0 = d0 * __expf(m0 - M2) + dno * __expf(mo - M2);
      m0 = M2;
      mo = __shfl_xor(m1, o); dno = __shfl_xor(d1, o);
      M2 = fmaxf(m1, mo);
      d1 = d1 * __expf(m1 - M2) + dno * __expf(mo - M2);
      m1 = M2;
    }
    for (int c = beg; c < end; c += 64) {
      int cnt = min(64, end - c);
      int srcv = 0; float x0 = -1e30f, x1 = -1e30f;
      if (l < cnt) {
        srcv = col_src[c + l];
        float2 sv = ((const float2*)s)[srcv];
        x0 = sv.x + dn0; x0 = x0 > 0.f ? x0 : 0.2f * x0;
        x1 = sv.y + dn1; x1 = x1 > 0.f ? x1 : 0.2f * x1;
      }
      float p0 = __expf(x0 - m0), p1 = __expf(x1 - m1);
      int offv = srcv << 9;
      for (int e = 0; e < cnt; e += 8) {
#pragma unroll
        for (int i = 0; i < 4; ++i) {
          int ep = e + 2 * i + hw;
          int off = __shfl(offv, ep & 63);
          float pa0 = __shfl(p0, ep & 63);
          float pa1 = __shfl(p1, ep & 63);
          float pa = hd ? pa1 : pa0;
          if (ep >= cnt) pa = 0.f;
          uint4 v = *(const uint4*)(hb + off);
          f32x2 pp = {pa, pa};
          A0 = __builtin_elementwise_fma(unp2(v.x), pp, A0);
          A1 = __builtin_elementwise_fma(unp2(v.y), pp, A1);
          A2 = __builtin_elementwise_fma(unp2(v.z), pp, A2);
          A3 = __builtin_elementwise_fma(unp2(v.w), pp, A3);
        }
      }
    }
  }

  A0.x += __shfl_xor(A0.x, 32); A0.y += __shfl_xor(A0.y, 32);
  A1.x += __shfl_xor(A1.x, 32); A1.y += __shfl_xor(A1.y, 32);
  A2.x += __shfl_xor(A2.x, 32); A2.y += __shfl_xor(A2.y, 32);
  A3.x += __shfl_xor(A3.x, 32); A3.y += __shfl_xor(A3.y, 32);

  if (hw == 0) {
    float dh = hd ? d1 : d0;
    float inv = 1.f / dh;
    float4 b0 = ((const float4*)bias)[2 * lh];
    float4 b1 = ((const float4*)bias)[2 * lh + 1];
    uint4 ov;
    ov.x = (uint_t)f2b(A0.x * inv + b0.x) | ((uint_t)f2b(A0.y * inv + b0.y) << 16);
    ov.y = (uint_t)f2b(A1.x * inv + b0.z) | ((uint_t)f2b(A1.y * inv + b0.w) << 16);
    ov.z = (uint_t)f2b(A2.x * inv + b1.x) | ((uint_t)f2b(A2.y * inv + b1.y) << 16);
    ov.w = (uint_t)f2b(A3.x * inv + b1.z) | ((uint_t)f2b(A3.y * inv + b1.w) << 16);
    out[(size_t)n * 32 + lh] = ov;
  }
}

// ------------- fused softmax + alpha + gather, H=1, f32 out (last layer)
__global__ __launch_bounds__(256) void k_agg1(const ushort_t* __restrict__ h2,
                                              const float* __restrict__ s,
                                              const float* __restrict__ dv,
                                              const int* __restrict__ row_ptr,
                                              const int* __restrict__ col_src,
                                              const float* __restrict__ bias,
                                              float* __restrict__ out) {
  int wid = threadIdx.x >> 6, l = threadIdx.x & 63;
  int n = blockIdx.x * 4 + wid;
  if (n >= NN) return;
  int beg = row_ptr[n], end = row_ptr[n + 1];
  int deg = end - beg;
  float dn0 = dv[n];
  int hw = l >> 4, lh = l & 15;
  const char* hb = (const char*)h2 + lh * 16;

  f32x2 A0 = {0.f, 0.f}, A1 = {0.f, 0.f}, A2 = {0.f, 0.f}, A3 = {0.f, 0.f};
  float d0;

  if (deg <= 64) {
    int srcv = 0; float x0 = -1e30f;
    if (l < deg) {
      srcv = col_src[beg + l];
      x0 = s[srcv] + dn0; x0 = x0 > 0.f ? x0 : 0.2f * x0;
    }
    int offv = srcv << 8;               // 256B rows

    uint4 P[6];
#pragma unroll
    for (int i = 0; i < 6; ++i)
      P[i] = *(const uint4*)(hb + __shfl(offv, 4 * i + hw));

    float m0 = x0;
#pragma unroll
    for (int o = 1; o < 64; o <<= 1) m0 = fmaxf(m0, __shfl_xor(m0, o));
    float p0 = __expf(x0 - m0);
    d0 = p0;
#pragma unroll
    for (int o = 1; o < 64; o <<= 1) d0 += __shfl_xor(d0, o);

#pragma unroll
    for (int i = 0; i < 6; ++i) {
      float pa = __shfl(p0, 4 * i + hw);
      f32x2 pp = {pa, pa};
      A0 = __builtin_elementwise_fma(unp2(P[i].x), pp, A0);
      A1 = __builtin_elementwise_fma(unp2(P[i].y), pp, A1);
      A2 = __builtin_elementwise_fma(unp2(P[i].z), pp, A2);
      A3 = __builtin_elementwise_fma(unp2(P[i].w), pp, A3);
    }
    for (int e = 24; e < deg; e += 8) {
#pragma unroll
      for (int i = 0; i < 2; ++i) {
        int ep = e + 4 * i + hw;
        int off = __shfl(offv, ep);
        float pa = __shfl(p0, ep);
        uint4 v = *(const uint4*)(hb + off);
        f32x2 pp = {pa, pa};
        A0 = __builtin_elementwise_fma(unp2(v.x), pp, A0);
        A1 = __builtin_elementwise_fma(unp2(v.y), pp, A1);
        A2 = __builtin_elementwise_fma(unp2(v.z), pp, A2);
        A3 = __builtin_elementwise_fma(unp2(v.w), pp, A3);
      }
    }
  } else {
    float m0 = -1e30f;
    d0 = 0.f;
    for (int e = beg + l; e < end; e += 64) {
      float x0 = s[col_src[e]] + dn0;
      x0 = x0 > 0.f ? x0 : 0.2f * x0;
      if (x0 > m0) { d0 = d0 * __expf(m0 - x0) + 1.f; m0 = x0; } else d0 += __expf(x0 - m0);
    }
#pragma unroll
    for (int o = 1; o < 64; o <<= 1) {
      float mo = __shfl_xor(m0, o), dno = __shfl_xor(d0, o);
      float M2 = fmaxf(m0, mo);
      d0 = d0 * __expf(m0 - M2) + dno * __expf(mo - M2);
      m0 = M2;
    }
    for (int c = beg; c < end; c += 64) {
      int cnt = min(64, end - c);
      int srcv = 0; float x0 = -1e30f;
      if (l < cnt) {
        srcv = col_src[c + l];
        x0 = s[srcv] + dn0; x0 = x0 > 0.f ? x0 : 0.2f * x0;
      }
      float p0 = __expf(x0 - m0);
      int offv = srcv << 8;
      for (int e = 0; e < cnt; e += 8) {
#pragma unroll
        for (int i = 0; i < 2; ++i) {
          int ep = e + 4 * i + hw;
          int off = __shfl(offv, ep & 63);
          float pa = __shfl(p0, ep & 63);
          if (ep >= cnt) pa = 0.f;
          uint4 v = *(const uint4*)(hb + off);
          f32x2 pp = {pa, pa};
          A0 = __builtin_elementwise_fma(unp2(v.x), pp, A0);
          A1 = __builtin_elementwise_fma(unp2(v.y), pp, A1);
          A2 = __builtin_elementwise_fma(unp2(v.z), pp, A2);
          A3 = __builtin_elementwise_fma(unp2(v.w), pp, A3);
        }
      }
    }
  }

#pragma unroll
  for (int o = 16; o < 64; o <<= 1) {
    A0.x += __shfl_xor(A0.x, o); A0.y += __shfl_xor(A0.y, o);
    A1.x += __shfl_xor(A1.x, o); A1.y += __shfl_xor(A1.y, o);
    A2.x += __shfl_xor(A2.x, o); A2.y += __shfl_xor(A2.y, o);
    A3.x += __shfl_xor(A3.x, o); A3.y += __shfl_xor(A3.y, o);
  }
  if (hw == 0) {
    float inv = 1.f / d0;
    float4 b0 = ((const float4*)bias)[2 * lh];
    float4 b1 = ((const float4*)bias)[2 * lh + 1];
    float4 o0 = make_float4(A0.x * inv + b0.x, A0.y * inv + b0.y,
                            A1.x * inv + b0.z, A1.y * inv + b0.w);
    float4 o1 = make_float4(A2.x * inv + b1.x, A2.y * inv + b1.y,
                            A3.x * inv + b1.z, A3.y * inv + b1.w);
    ((float4*)out)[(size_t)n * 32 + 2 * lh] = o0;
    ((float4*)out)[(size_t)n * 32 + 2 * lh + 1] = o1;
  }
}

// ---------------------------------------------------------------- launch
extern "C" void kernel_launch(void* const* d_in, const int* in_sizes, int n_in,
                              void* d_out, int out_size, void* d_ws, size_t ws_size,
                              hipStream_t stream) {
  const float* x     = (const float*)d_in[0];
  const int*   edge  = (const int*)d_in[1];
  const float* fc_w  = (const float*)d_in[2];
  const float* fc_b  = (const float*)d_in[3];
  const float* W1    = (const float*)d_in[4];
  const float* asrc1 = (const float*)d_in[5];
  const float* adst1 = (const float*)d_in[6];
  const float* b1    = (const float*)d_in[7];
  const float* Wm    = (const float*)d_in[8];
  const float* asrcm = (const float*)d_in[9];
  const float* adstm = (const float*)d_in[10];
  const float* bm    = (const float*)d_in[11];
  const float* W6    = (const float*)d_in[12];
  const float* asrc6 = (const float*)d_in[13];
  const float* adst6 = (const float*)d_in[14];
  const float* b6    = (const float*)d_in[15];

  char* w = (char*)d_ws;
  size_t off = 0;
  auto carve = [&](size_t bytes) -> char* {
    char* p = w + off;
    off = (off + bytes + 255) & ~(size_t)255;
    return p;
  };
  ushort_t* feat0 = (ushort_t*)carve((size_t)NN * 256 * 2);
  ushort_t* feat1 = (ushort_t*)carve((size_t)NN * 256 * 2);
  ushort_t* hbuf  = (ushort_t*)carve((size_t)NN * 256 * 2);
  float* sbuf   = (float*)carve((size_t)NN * 2 * 4);
  float* dbuf   = (float*)carve((size_t)NN * 2 * 4);
  ushort_t* fcWt = (ushort_t*)carve((size_t)128 * 64 * 2);
  ushort_t* W1t  = (ushort_t*)carve((size_t)256 * 128 * 2);
  ushort_t* Wmt  = (ushort_t*)carve((size_t)4 * 256 * 256 * 2);
  ushort_t* W6t  = (ushort_t*)carve((size_t)128 * 256 * 2);
  int* counts   = (int*)carve((size_t)NN * 4);
  int* row_ptr  = (int*)carve((size_t)(NN + 1) * 4);
  int* cursor   = (int*)carve((size_t)NN * 4);
  int* col_src  = (int*)carve((size_t)ET * 4);
  int* scn      = (int*)carve((size_t)NN * 4);
  int* bsum     = (int*)carve((size_t)64 * 4);
  int* boff     = (int*)carve((size_t)64 * 4);
  (void)ws_size;

  // weight prep
  k_prep_w<<<(335872 + 255) / 256, 256, 0, stream>>>(fc_w, W1, Wm, W6, fcWt, W1t, Wmt, W6t);

  // CSR build
  hipMemsetAsync(counts, 0, (size_t)NN * 4, stream);
  int eb = (ET + 255) / 256;
  const int NB = (NN + 1023) / 1024;   // 49
  k_count<<<eb, 256, 0, stream>>>(edge, counts);
  k_scan1<<<NB, 1024, 0, stream>>>(counts, scn, bsum);
  k_scan2<<<1, 64, 0, stream>>>(bsum, boff);
  k_scan3<<<NB, 1024, 0, stream>>>(scn, boff, row_ptr, cursor);
  k_fill<<<eb, 256, 0, stream>>>(edge, cursor, col_src);

  dim3 g1((NN + 127) / 128, 1), g2((NN + 127) / 128, 2);
  int ab = (NN + 3) / 4;

  auto gat = [&](const ushort_t* in, int K, const ushort_t* Wt, const float* a_s,
                 const float* a_d, const float* bias, void* outp, int H) {
    k_gemm64<<<(H == 2 ? g2 : g1), 256, 0, stream>>>(
        in, Wt, hbuf, NN, K, H * 128, a_s, a_d, sbuf, dbuf, H);
    if (H == 2)
      k_agg2<<<ab, 256, 0, stream>>>(hbuf, sbuf, dbuf, row_ptr, col_src, bias, (uint4*)outp);
    else
      k_agg1<<<ab, 256, 0, stream>>>(hbuf, sbuf, dbuf, row_ptr, col_src, bias, (float*)outp);
  };

  // fc: relu(x @ fc_w + fc_b) -> feat0 bf16 [N,128]
  k_gemm_f32<<<g1, 256, 0, stream>>>(x, fcWt, feat0, NN, 64, 128, fc_b);

  // layer 1: 128 -> 2x128 concat
  gat(feat0, 128, W1t, asrc1, adst1, b1, feat1, 2);

  // middle layers: 256 -> 2x128 concat (ping-pong)
  const ushort_t* cur = feat1;
  ushort_t* nxt = feat0;
  for (int i = 0; i < 4; ++i) {
    gat(cur, 256, Wmt + (size_t)i * 256 * 256, asrcm + (size_t)i * 2 * 128,
        adstm + (size_t)i * 2 * 128, bm + (size_t)i * 256, nxt, 2);
    const ushort_t* tmp = cur;
    cur = nxt;
    nxt = (ushort_t*)tmp;
  }

  // layer 6: 256 -> 1x128, f32 out to d_out
  gat(cur, 256, W6t, asrc6, adst6, b6, d_out, 1);
}